// Round 13
// baseline (299.256 us; speedup 1.0000x reference)
//
#include <hip/hip_runtime.h>

// CrossAttention: B=16, Sq=4096, Dm=512, Skv=77, Dc=768, H=8, Dh=64, inner=512
// Single-pass fp16 MFMA pipeline.
//   0. pad_fill : zero vT si-pad + kbuf row-pad
//   1. transpose4: all W* fp32 [K][512] -> fp16 [512][K] in one launch  (ws)
//   2. gemm_ctx OUT_H : k = ctx@Wk -> fp16 [1240pad][512]               (ws)
//      gemm_ctx OUT_HT: v = ctx@Wv -> Vt fp16 [16][512][96pad]          (ws)
//   3. gemm_x16 : q = x(fp32)@Wq -> fp16 [65536][512]  (cvt fused)      (ws)
//   4. attnout  : FUSED attention + out-projection. Attn result lives in
//                 a 128x512 XOR-swizzled LDS tile (never hits HBM); the
//                 out-proj GEMM reads A from LDS, stages only Wout (L2).
//                 160 KiB LDS/block, all-__syncthreads sync.  -> d_out
// Big GEMM gemm_x16: 128x256 tile, dbuf LDS, issue-early loads (R12-proven).

typedef unsigned short u16;
typedef unsigned int u32;
typedef _Float16 f16;
typedef __attribute__((ext_vector_type(8))) _Float16 half8;
typedef __attribute__((ext_vector_type(4))) _Float16 half4;
typedef __attribute__((ext_vector_type(4))) float f32x4;

__device__ __forceinline__ f32x4 mfma16h(half8 a, half8 b, f32x4 c) {
    return __builtin_amdgcn_mfma_f32_16x16x32_f16(a, b, c, 0, 0, 0);
}
// async global->LDS, 16B per lane; LDS dest = wave-uniform base + lane*16
__device__ __forceinline__ void gl_lds16(const f16* g, f16* l) {
    __builtin_amdgcn_global_load_lds(
        (const __attribute__((address_space(1))) void*)g,
        (__attribute__((address_space(3))) void*)l, 16, 0, 0);
}

// ---------------- pad fill ----------------
__global__ __launch_bounds__(256) void pad_fill(
    f16* __restrict__ vT, f16* __restrict__ kbuf)
{
    const int nv = 16 * 512 * 19;
    int i = blockIdx.x * 256 + threadIdx.x;
    if (i < nv) {
        int g = i / 19, s = i - g * 19;
        vT[(size_t)g * 96 + 77 + s] = (f16)0.f;
    } else {
        int j = i - nv;
        if (j < 8 * 512) kbuf[(size_t)1232 * 512 + j] = (f16)0.f;
    }
}

// ---------------- all 4 weight transposes -> fp16, one launch ----------------
__global__ __launch_bounds__(256) void transpose4(
    const float* __restrict__ Wq, const float* __restrict__ Wk,
    const float* __restrict__ Wv, const float* __restrict__ Wo,
    f16* __restrict__ WqT, f16* __restrict__ WkT,
    f16* __restrict__ WvT, f16* __restrict__ WoT)
{
    int idx = blockIdx.x * 256 + threadIdx.x;
    const float* W; f16* T; int K; int base;
    if (idx < 262144)        { W = Wq; T = WqT; K = 512; base = 0; }
    else if (idx < 655360)   { W = Wk; T = WkT; K = 768; base = 262144; }
    else if (idx < 1048576)  { W = Wv; T = WvT; K = 768; base = 655360; }
    else if (idx < 1310720)  { W = Wo; T = WoT; K = 512; base = 1048576; }
    else return;
    int j = idx - base;
    int n = j / K, k = j - n * K;
    T[j] = (f16)W[(size_t)k * 512 + n];
}

#define OUT_H   1
#define OUT_HT  2

// ---------------- q-proj GEMM: fused fp32->fp16, 128x256 tile (R12) --------
__global__ __launch_bounds__(256, 2) void gemm_x16(
    const float* __restrict__ A, const f16* __restrict__ B,
    f16* __restrict__ CHalf, int M, int N, int K)
{
    __shared__ f16 sA[2][128 * 32];
    __shared__ f16 sB[2][256 * 32];

    const int t = threadIdx.x;
    const int lane = t & 63;
    const int w = t >> 6;
    const int wr = w >> 1, wc = w & 1;

    const int f = blockIdx.x + gridDim.x * blockIdx.y;
    const int cpx = (gridDim.x * gridDim.y) >> 3;
    const int logical = (f & 7) * cpx + (f >> 3);
    const int m0 = (logical / gridDim.x) * 128;
    const int n0 = (logical % gridDim.x) * 256;

    const int ar = lane & 15;
    const int kc = (lane >> 4) << 3;

    const int arow = t >> 1;
    const int acol = (t & 1) << 4;
    const int brow = lane >> 2;
    const int bcol = (lane & 3) << 3;

    f32x4 acc[4][8] = {};
    f32x4 rA[4];

    auto LOAD_A = [&](int kt) {
        const float* p = A + (size_t)(m0 + arow) * K + (kt << 5) + acol;
        #pragma unroll
        for (int j = 0; j < 4; ++j) rA[j] = *(const f32x4*)(p + j * 4);
    };
    auto WRITE_A = [&](int buf) {
        half8 h0 = { (f16)rA[0].x, (f16)rA[0].y, (f16)rA[0].z, (f16)rA[0].w,
                     (f16)rA[1].x, (f16)rA[1].y, (f16)rA[1].z, (f16)rA[1].w };
        half8 h1 = { (f16)rA[2].x, (f16)rA[2].y, (f16)rA[2].z, (f16)rA[2].w,
                     (f16)rA[3].x, (f16)rA[3].y, (f16)rA[3].z, (f16)rA[3].w };
        *(half8*)(&sA[buf][arow * 32 + acol])     = h0;
        *(half8*)(&sA[buf][arow * 32 + acol + 8]) = h1;
    };
    auto STAGE_B = [&](int buf, int kt) {
        #pragma unroll
        for (int j = 0; j < 4; ++j) {
            const int ci = w * 4 + j;
            gl_lds16(B + (size_t)(n0 + ci * 16 + brow) * K + (kt << 5) + bcol,
                     &sB[buf][ci * 512]);
        }
    };

    const int nk = K >> 5;
    LOAD_A(0);
    STAGE_B(0, 0);
    WRITE_A(0);
    __syncthreads();

    int cur = 0;
    for (int kt = 0; kt < nk; ++kt) {
        if (kt + 1 < nk) {
            LOAD_A(kt + 1);
            STAGE_B(cur ^ 1, kt + 1);
        }

        half8 fa[4], fb[8];
        #pragma unroll
        for (int m = 0; m < 4; ++m)
            fa[m] = *(const half8*)(&sA[cur][(wr * 64 + m * 16 + ar) * 32 + kc]);
        #pragma unroll
        for (int n = 0; n < 8; ++n)
            fb[n] = *(const half8*)(&sB[cur][(wc * 128 + n * 16 + ar) * 32 + kc]);

        __builtin_amdgcn_s_setprio(1);
        #pragma unroll
        for (int m = 0; m < 4; ++m)
            #pragma unroll
            for (int n = 0; n < 8; ++n)
                acc[m][n] = mfma16h(fa[m], fb[n], acc[m][n]);
        __builtin_amdgcn_s_setprio(0);

        if (kt + 1 < nk) WRITE_A(cur ^ 1);
        __syncthreads();
        cur ^= 1;
    }

    #pragma unroll
    for (int n = 0; n < 8; ++n) {
        int col = n0 + wc * 128 + n * 16 + ar;
        #pragma unroll
        for (int m = 0; m < 4; ++m) {
            #pragma unroll
            for (int r = 0; r < 4; ++r) {
                int row = m0 + wr * 64 + m * 16 + ((lane >> 4) << 2) + r;
                CHalf[(size_t)row * N + col] = (f16)acc[m][n][r];
            }
        }
    }
}

// ---------------- ctx GEMM (kv projections, reg-staged fp32->fp16) ----------
#define PK 40

template<int OUTM>
__global__ __launch_bounds__(256) void gemm_ctx(
    const float* __restrict__ A, const f16* __restrict__ Bt,
    f16* __restrict__ CH, int M, int N, int K)
{
    __shared__ f16 lA[128 * PK];
    __shared__ f16 lB[128 * PK];

    const int t = threadIdx.x;
    const int lane = t & 63;
    const int wid = t >> 6;
    const int wr = wid >> 1, wc = wid & 1;
    const int m0 = blockIdx.x * 128, n0 = blockIdx.y * 128;
    const int ar = lane & 15;
    const int kc = (lane >> 4) << 3;

    f32x4 acc[4][4] = {};

    for (int k0 = 0; k0 < K; k0 += 32) {
        #pragma unroll
        for (int it = 0; it < 4; ++it) {
            int idx = t + it * 256;
            int row = idx >> 3;
            int c4 = (idx & 7) << 2;
            int gr = m0 + row;
            float4 v = make_float4(0.f, 0.f, 0.f, 0.f);
            if (gr < M) v = *(const float4*)(A + (size_t)gr * K + k0 + c4);
            *(half4*)(lA + row * PK + c4) = (half4){(f16)v.x, (f16)v.y, (f16)v.z, (f16)v.w};
        }
        #pragma unroll
        for (int it = 0; it < 2; ++it) {
            int idx = t + it * 256;
            int row = idx >> 2;
            int c8 = (idx & 3) << 3;
            *(half8*)(lB + row * PK + c8) =
                *(const half8*)(Bt + (size_t)(n0 + row) * K + k0 + c8);
        }
        __syncthreads();

        half8 fa[4], fb[4];
        #pragma unroll
        for (int m = 0; m < 4; ++m)
            fa[m] = *(const half8*)(lA + (wr * 64 + m * 16 + ar) * PK + kc);
        #pragma unroll
        for (int n = 0; n < 4; ++n)
            fb[n] = *(const half8*)(lB + (wc * 64 + n * 16 + ar) * PK + kc);
        #pragma unroll
        for (int m = 0; m < 4; ++m)
            #pragma unroll
            for (int n = 0; n < 4; ++n)
                acc[m][n] = mfma16h(fa[m], fb[n], acc[m][n]);
        __syncthreads();
    }

    #pragma unroll
    for (int n = 0; n < 4; ++n) {
        int col = n0 + wc * 64 + n * 16 + ar;
        #pragma unroll
        for (int m = 0; m < 4; ++m) {
            #pragma unroll
            for (int r = 0; r < 4; ++r) {
                int row = m0 + wr * 64 + m * 16 + ((lane >> 4) << 2) + r;
                if (row < M) {
                    float v = acc[m][n][r];
                    if constexpr (OUTM == OUT_H) {
                        CH[(size_t)row * N + col] = (f16)v;
                    } else {
                        int bb = row / 77;
                        int si = row - bb * 77;
                        CH[((size_t)bb * 512 + col) * 96 + si] = (f16)v;
                    }
                }
            }
        }
    }
}

// ---------------- FUSED attention + out-projection ----------------
// grid dim3(32, 16) = (128-row tile, batch), block 512 (8 waves).
// Phase 1: attention (8 heads, 16 rows/wave) -> sAT swizzled LDS tile.
// Phase 2: C = sAT @ WoT + bias, two 256-col halves; A from LDS (swizzled),
//          B via gl_lds dbuf. 160 KiB LDS total.
__global__ __launch_bounds__(512) void attnout(
    const f16* __restrict__ q, const f16* __restrict__ kbuf,
    const f16* __restrict__ vT, const f16* __restrict__ WoT,
    const float* __restrict__ bias, float* __restrict__ C)
{
    __shared__ f16 sAT[128 * 512];    // 128 KB attn tile, col ^= (row&7)<<3
    __shared__ f16 sB[2][256 * 32];   // 32 KB (phase 1: P overlay)

    const int t = threadIdx.x;
    const int lane = t & 63;
    const int w = t >> 6;             // 0..7
    const int ar = lane & 15;
    const int kg = lane >> 4;         // 0..3
    const int kc = kg << 3;

    const int b = blockIdx.y;
    const int row0 = blockIdx.x * 128;
    const size_t qrow0 = (size_t)b * 4096 + row0;

    // ================= phase 1: attention =================
    f16* myP = (f16*)sB + w * 16 * 104;   // wave-private P [16][104]
    const int wrow = w * 16;

    for (int i = lane; i < 16 * 12; i += 64) {      // zero P pad cols 80..103
        int row = i / 12, c = 80 + (i % 12) * 2;
        *(u32*)(myP + row * 104 + c) = 0;
    }

    #pragma unroll 1
    for (int head = 0; head < 8; ++head) {
        // scores [16 q][80 si]
        f32x4 accs[5] = {};
        #pragma unroll
        for (int ks = 0; ks < 2; ++ks) {
            const int d = head * 64 + ks * 32 + kc;
            half8 ah = *(const half8*)(q + (qrow0 + wrow + ar) * 512 + d);
            #pragma unroll
            for (int n = 0; n < 5; ++n) {
                half8 bh = *(const half8*)(kbuf + (size_t)(b * 77 + n * 16 + ar) * 512 + d);
                accs[n] = mfma16h(ah, bh, accs[n]);
            }
        }
        // softmax (row = kg*4 + r; 16-lane-group reduce)
        #pragma unroll
        for (int r = 0; r < 4; ++r) {
            float mx = -1e30f;
            #pragma unroll
            for (int n = 0; n < 5; ++n) {
                float v = accs[n][r] * 0.125f;
                if (n == 4 && ar >= 13) v = -1e30f;   // mask si >= 77
                accs[n][r] = v;
                mx = fmaxf(mx, v);
            }
            mx = fmaxf(mx, __shfl_xor(mx, 1));
            mx = fmaxf(mx, __shfl_xor(mx, 2));
            mx = fmaxf(mx, __shfl_xor(mx, 4));
            mx = fmaxf(mx, __shfl_xor(mx, 8));
            float sum = 0.f;
            #pragma unroll
            for (int n = 0; n < 5; ++n) {
                float e = __expf(accs[n][r] - mx);
                accs[n][r] = e;
                sum += e;
            }
            sum += __shfl_xor(sum, 1);
            sum += __shfl_xor(sum, 2);
            sum += __shfl_xor(sum, 4);
            sum += __shfl_xor(sum, 8);
            float inv = 1.f / sum;
            #pragma unroll
            for (int n = 0; n < 5; ++n) accs[n][r] *= inv;
        }
        // P -> myP (wave-private)
        #pragma unroll
        for (int n = 0; n < 5; ++n)
            #pragma unroll
            for (int r = 0; r < 4; ++r)
                myP[(kg * 4 + r) * 104 + n * 16 + ar] = (f16)accs[n][r];
        // PV [16 q][64 d], K-dim 96 (zero-padded)
        f32x4 accp[4] = {};
        #pragma unroll
        for (int ks = 0; ks < 3; ++ks) {
            half8 pa = *(const half8*)(myP + ar * 104 + ks * 32 + kc);
            #pragma unroll
            for (int n = 0; n < 4; ++n) {
                half8 bh = *(const half8*)(vT +
                    ((size_t)b * 512 + head * 64 + n * 16 + ar) * 96 + ks * 32 + kc);
                accp[n] = mfma16h(pa, bh, accp[n]);
            }
        }
        // attn result -> sAT (swizzled)
        #pragma unroll
        for (int n = 0; n < 4; ++n)
            #pragma unroll
            for (int r = 0; r < 4; ++r) {
                int row = wrow + kg * 4 + r;
                int col = head * 64 + n * 16 + ar;
                sAT[row * 512 + (col ^ ((row & 7) << 3))] = (f16)accp[n][r];
            }
    }
    __syncthreads();   // attn tile complete; P region dead

    // ================= phase 2: out-projection =================
    const int wr2 = w >> 2, wc2 = w & 3;     // 2M x 4N waves, wave tile 64x64
    const int srow = lane >> 2;
    const int scol = (lane & 3) << 3;

    #pragma unroll 1
    for (int nh = 0; nh < 2; ++nh) {
        const int n0 = nh * 256;
        f32x4 acc[4][4] = {};

        auto STAGE_B = [&](int buf, int kt) {
            #pragma unroll
            for (int j = 0; j < 2; ++j) {
                const int ci = w * 2 + j;    // chunk 0..15 -> rows ci*16..+15
                gl_lds16(WoT + (size_t)(n0 + ci * 16 + srow) * 512 + (kt << 5) + scol,
                         &sB[buf][ci * 512]);
            }
        };
        STAGE_B(0, 0);
        __syncthreads();

        int cur = 0;
        #pragma unroll 1
        for (int kt = 0; kt < 16; ++kt) {
            if (kt + 1 < 16) STAGE_B(cur ^ 1, kt + 1);

            half8 fa[4], fb[4];
            #pragma unroll
            for (int m = 0; m < 4; ++m) {
                int row = wr2 * 64 + m * 16 + ar;
                int cl = (kt * 32 + kc) ^ ((row & 7) << 3);
                fa[m] = *(const half8*)(&sAT[row * 512 + cl]);
            }
            #pragma unroll
            for (int n = 0; n < 4; ++n)
                fb[n] = *(const half8*)(&sB[cur][(wc2 * 64 + n * 16 + ar) * 32 + kc]);

            __builtin_amdgcn_s_setprio(1);
            #pragma unroll
            for (int m = 0; m < 4; ++m)
                #pragma unroll
                for (int n = 0; n < 4; ++n)
                    acc[m][n] = mfma16h(fa[m], fb[n], acc[m][n]);
            __builtin_amdgcn_s_setprio(0);
            __syncthreads();
            cur ^= 1;
        }

        #pragma unroll
        for (int n = 0; n < 4; ++n) {
            int col = n0 + wc2 * 64 + n * 16 + ar;
            float bv = bias[col];
            #pragma unroll
            for (int m = 0; m < 4; ++m) {
                #pragma unroll
                for (int r = 0; r < 4; ++r) {
                    int row = wr2 * 64 + m * 16 + kg * 4 + r;
                    C[(qrow0 + row) * 512 + col] = acc[m][n][r] + bv;
                }
            }
        }
        // last K-iter ended with __syncthreads: sB reads done, safe to restage
    }
}

extern "C" void kernel_launch(void* const* d_in, const int* in_sizes, int n_in,
                              void* d_out, int out_size, void* d_ws, size_t ws_size,
                              hipStream_t stream)
{
    const float* x    = (const float*)d_in[0];   // [16,4096,512]
    const float* ctx  = (const float*)d_in[1];   // [16,77,768]
    const float* Wq   = (const float*)d_in[2];   // [512,512]
    const float* Wk   = (const float*)d_in[3];   // [768,512]
    const float* Wv   = (const float*)d_in[4];   // [768,512]
    const float* Wout = (const float*)d_in[5];   // [512,512]
    const float* bout = (const float*)d_in[6];   // [512]

    char* ws = (char*)d_ws;
    size_t off = 0;
    auto alloc = [&](size_t bytes) -> void* {
        void* p = ws + off;
        off += (bytes + 255) & ~(size_t)255;
        return p;
    };
    f16* WqT = (f16*)alloc(512 * 512 * 2);
    f16* WkT = (f16*)alloc(768 * 512 * 2);
    f16* WvT = (f16*)alloc(768 * 512 * 2);
    f16* WoT = (f16*)alloc(512 * 512 * 2);
    f16* kbuf = (f16*)alloc((size_t)1240 * 512 * 2);     // 1232 rows + zero pad
    f16* vT   = (f16*)alloc((size_t)16 * 512 * 96 * 2);  // [b][col][si pad 96]
    f16* qh   = (f16*)alloc((size_t)65536 * 512 * 2);    // q fp16 (64 MiB, ws)
    (void)ws_size; (void)in_sizes; (void)n_in; (void)out_size;

    // 0. zero pads
    pad_fill<<<dim3(625), dim3(256), 0, stream>>>(vT, kbuf);

    // 1. weight transposes -> fp16 (one launch)
    transpose4<<<dim3(5120), dim3(256), 0, stream>>>(
        Wq, Wk, Wv, Wout, WqT, WkT, WvT, WoT);

    // 2. k/v projections
    gemm_ctx<OUT_H><<<dim3(10, 4), dim3(256), 0, stream>>>(
        ctx, WkT, kbuf, 1232, 512, 768);
    gemm_ctx<OUT_HT><<<dim3(10, 4), dim3(256), 0, stream>>>(
        ctx, WvT, vT, 1232, 512, 768);

    // 3. q projection (cvt fused): x fp32 @ WqT -> q fp16 in ws
    gemm_x16<<<dim3(2, 512), dim3(256), 0, stream>>>(
        x, WqT, qh, 65536, 512, 512);

    // 4. fused attention + out-projection -> d_out fp32
    attnout<<<dim3(32, 16), dim3(512), 0, stream>>>(
        qh, kbuf, vT, WoT, bout, (float*)d_out);
}

// Round 14
// 298.088 us; speedup vs baseline: 1.0039x; 1.0039x over previous
//
#include <hip/hip_runtime.h>

// CrossAttention: B=16, Sq=4096, Dm=512, Skv=77, Dc=768, H=8, Dh=64, inner=512
// Single-pass fp16 MFMA pipeline (R12 structure; out-proj now counted-vmcnt).
//   0. pad_fill : zero vT si-pad + kbuf row-pad
//   1. transpose4: all W* fp32 [K][512] -> fp16 [512][K] in one launch  (ws)
//   2. gemm_ctx OUT_H : k = ctx@Wk -> fp16 [1240pad][512]               (ws)
//      gemm_ctx OUT_HT: v = ctx@Wv -> Vt fp16 [16][512][96pad]          (ws)
//   3. gemm_x16 : q = x(fp32)@Wq -> fp16 [65536][512]  (cvt fused)      (ws)
//   4. attn_h16 : MFMA scores + in-reg fp32 softmax + MFMA PV           (ws)
//   5. gemm_h16 : out = attn@Wout + bout -> fp32. T3/T4 pipeline:
//                 2-tile-deep global_load_lds prefetch, counted vmcnt(6)
//                 (never drained in-loop), raw s_barrier pairs.  -> d_out

typedef unsigned short u16;
typedef unsigned int u32;
typedef _Float16 f16;
typedef __attribute__((ext_vector_type(8))) _Float16 half8;
typedef __attribute__((ext_vector_type(4))) _Float16 half4;
typedef __attribute__((ext_vector_type(4))) float f32x4;

__device__ __forceinline__ f32x4 mfma16h(half8 a, half8 b, f32x4 c) {
    return __builtin_amdgcn_mfma_f32_16x16x32_f16(a, b, c, 0, 0, 0);
}
// async global->LDS, 16B per lane; LDS dest = wave-uniform base + lane*16
__device__ __forceinline__ void gl_lds16(const f16* g, f16* l) {
    __builtin_amdgcn_global_load_lds(
        (const __attribute__((address_space(1))) void*)g,
        (__attribute__((address_space(3))) void*)l, 16, 0, 0);
}

// ---------------- pad fill ----------------
__global__ __launch_bounds__(256) void pad_fill(
    f16* __restrict__ vT, f16* __restrict__ kbuf)
{
    const int nv = 16 * 512 * 19;
    int i = blockIdx.x * 256 + threadIdx.x;
    if (i < nv) {
        int g = i / 19, s = i - g * 19;
        vT[(size_t)g * 96 + 77 + s] = (f16)0.f;
    } else {
        int j = i - nv;
        if (j < 8 * 512) kbuf[(size_t)1232 * 512 + j] = (f16)0.f;
    }
}

// ---------------- all 4 weight transposes -> fp16, one launch ----------------
__global__ __launch_bounds__(256) void transpose4(
    const float* __restrict__ Wq, const float* __restrict__ Wk,
    const float* __restrict__ Wv, const float* __restrict__ Wo,
    f16* __restrict__ WqT, f16* __restrict__ WkT,
    f16* __restrict__ WvT, f16* __restrict__ WoT)
{
    int idx = blockIdx.x * 256 + threadIdx.x;
    const float* W; f16* T; int K; int base;
    if (idx < 262144)        { W = Wq; T = WqT; K = 512; base = 0; }
    else if (idx < 655360)   { W = Wk; T = WkT; K = 768; base = 262144; }
    else if (idx < 1048576)  { W = Wv; T = WvT; K = 768; base = 655360; }
    else if (idx < 1310720)  { W = Wo; T = WoT; K = 512; base = 1048576; }
    else return;
    int j = idx - base;
    int n = j / K, k = j - n * K;
    T[j] = (f16)W[(size_t)k * 512 + n];
}

#define OUT_H   1
#define OUT_HT  2

// ---------------- q-proj GEMM: fused fp32->fp16, 128x256 tile (R12) --------
__global__ __launch_bounds__(256, 2) void gemm_x16(
    const float* __restrict__ A, const f16* __restrict__ B,
    f16* __restrict__ CHalf, int M, int N, int K)
{
    __shared__ f16 sA[2][128 * 32];
    __shared__ f16 sB[2][256 * 32];

    const int t = threadIdx.x;
    const int lane = t & 63;
    const int w = t >> 6;
    const int wr = w >> 1, wc = w & 1;

    const int f = blockIdx.x + gridDim.x * blockIdx.y;
    const int cpx = (gridDim.x * gridDim.y) >> 3;
    const int logical = (f & 7) * cpx + (f >> 3);
    const int m0 = (logical / gridDim.x) * 128;
    const int n0 = (logical % gridDim.x) * 256;

    const int ar = lane & 15;
    const int kc = (lane >> 4) << 3;

    const int arow = t >> 1;
    const int acol = (t & 1) << 4;
    const int brow = lane >> 2;
    const int bcol = (lane & 3) << 3;

    f32x4 acc[4][8] = {};
    f32x4 rA[4];

    auto LOAD_A = [&](int kt) {
        const float* p = A + (size_t)(m0 + arow) * K + (kt << 5) + acol;
        #pragma unroll
        for (int j = 0; j < 4; ++j) rA[j] = *(const f32x4*)(p + j * 4);
    };
    auto WRITE_A = [&](int buf) {
        half8 h0 = { (f16)rA[0].x, (f16)rA[0].y, (f16)rA[0].z, (f16)rA[0].w,
                     (f16)rA[1].x, (f16)rA[1].y, (f16)rA[1].z, (f16)rA[1].w };
        half8 h1 = { (f16)rA[2].x, (f16)rA[2].y, (f16)rA[2].z, (f16)rA[2].w,
                     (f16)rA[3].x, (f16)rA[3].y, (f16)rA[3].z, (f16)rA[3].w };
        *(half8*)(&sA[buf][arow * 32 + acol])     = h0;
        *(half8*)(&sA[buf][arow * 32 + acol + 8]) = h1;
    };
    auto STAGE_B = [&](int buf, int kt) {
        #pragma unroll
        for (int j = 0; j < 4; ++j) {
            const int ci = w * 4 + j;
            gl_lds16(B + (size_t)(n0 + ci * 16 + brow) * K + (kt << 5) + bcol,
                     &sB[buf][ci * 512]);
        }
    };

    const int nk = K >> 5;
    LOAD_A(0);
    STAGE_B(0, 0);
    WRITE_A(0);
    __syncthreads();

    int cur = 0;
    for (int kt = 0; kt < nk; ++kt) {
        if (kt + 1 < nk) {
            LOAD_A(kt + 1);
            STAGE_B(cur ^ 1, kt + 1);
        }

        half8 fa[4], fb[8];
        #pragma unroll
        for (int m = 0; m < 4; ++m)
            fa[m] = *(const half8*)(&sA[cur][(wr * 64 + m * 16 + ar) * 32 + kc]);
        #pragma unroll
        for (int n = 0; n < 8; ++n)
            fb[n] = *(const half8*)(&sB[cur][(wc * 128 + n * 16 + ar) * 32 + kc]);

        __builtin_amdgcn_s_setprio(1);
        #pragma unroll
        for (int m = 0; m < 4; ++m)
            #pragma unroll
            for (int n = 0; n < 8; ++n)
                acc[m][n] = mfma16h(fa[m], fb[n], acc[m][n]);
        __builtin_amdgcn_s_setprio(0);

        if (kt + 1 < nk) WRITE_A(cur ^ 1);
        __syncthreads();
        cur ^= 1;
    }

    #pragma unroll
    for (int n = 0; n < 8; ++n) {
        int col = n0 + wc * 128 + n * 16 + ar;
        #pragma unroll
        for (int m = 0; m < 4; ++m) {
            #pragma unroll
            for (int r = 0; r < 4; ++r) {
                int row = m0 + wr * 64 + m * 16 + ((lane >> 4) << 2) + r;
                CHalf[(size_t)row * N + col] = (f16)acc[m][n][r];
            }
        }
    }
}

// ---------------- out-proj GEMM: 128x256, counted-vmcnt T3/T4 pipeline -----
// A fp16 [M][K], B fp16 [N][K]; grid dim3(N/256, M/128), block 256. K/32 = 16.
__global__ __launch_bounds__(256, 2) void gemm_h16(
    const f16* __restrict__ A, const f16* __restrict__ B,
    const float* __restrict__ bias, float* __restrict__ C,
    int M, int N, int K)
{
    __shared__ f16 sA[2][128 * 32];   // 8 KB each
    __shared__ f16 sB[2][256 * 32];   // 16 KB each (48 KB total)

    const int t = threadIdx.x;
    const int lane = t & 63;
    const int w = t >> 6;
    const int wr = w >> 1, wc = w & 1;

    const int f = blockIdx.x + gridDim.x * blockIdx.y;
    const int cpx = (gridDim.x * gridDim.y) >> 3;
    const int logical = (f & 7) * cpx + (f >> 3);
    const int m0 = (logical / gridDim.x) * 128;
    const int n0 = (logical % gridDim.x) * 256;

    const int ar = lane & 15;
    const int kc = (lane >> 4) << 3;
    const int srow = lane >> 2;
    const int scol = (lane & 3) << 3;

    f32x4 acc[4][8] = {};

    // 6 gl_lds per thread per K-tile (A: 2 chunks, B: 4 chunks)
    auto STAGE = [&](int buf, int kt) {
        #pragma unroll
        for (int j = 0; j < 2; ++j) {
            const int ci = w * 2 + j;
            gl_lds16(A + (size_t)(m0 + ci * 16 + srow) * K + (kt << 5) + scol,
                     &sA[buf][ci * 512]);
        }
        #pragma unroll
        for (int j = 0; j < 4; ++j) {
            const int ci = w * 4 + j;
            gl_lds16(B + (size_t)(n0 + ci * 16 + srow) * K + (kt << 5) + scol,
                     &sB[buf][ci * 512]);
        }
    };

    // prologue: 2 tiles in flight = 12 outstanding loads/thread
    STAGE(0, 0);
    STAGE(1, 1);
    asm volatile("s_waitcnt vmcnt(6)" ::: "memory");   // tile0 landed; tile1 flies
    __builtin_amdgcn_s_barrier();

    const int NK = 16;
    for (int kt = 0; kt < NK; ++kt) {
        const int cur = kt & 1;
        // entry invariant: buf[cur] = tile kt (landed+barrier'd);
        //                  tile kt+1's 6 loads in flight.
        half8 fa[4], fb[8];
        #pragma unroll
        for (int m = 0; m < 4; ++m)
            fa[m] = *(const half8*)(&sA[cur][(wr * 64 + m * 16 + ar) * 32 + kc]);
        #pragma unroll
        for (int n = 0; n < 8; ++n)
            fb[n] = *(const half8*)(&sB[cur][(wc * 128 + n * 16 + ar) * 32 + kc]);
        asm volatile("s_waitcnt lgkmcnt(0)" ::: "memory");   // my frag reads done
        __builtin_amdgcn_sched_barrier(0);
        __builtin_amdgcn_s_barrier();                        // ALL waves read buf[cur]

        if (kt + 2 < NK) STAGE(cur, kt + 2);   // overwrite buf[cur]; 6+6=12 in flight

        __builtin_amdgcn_s_setprio(1);
        #pragma unroll
        for (int m = 0; m < 4; ++m)
            #pragma unroll
            for (int n = 0; n < 8; ++n)
                acc[m][n] = mfma16h(fa[m], fb[n], acc[m][n]);
        __builtin_amdgcn_s_setprio(0);

        // wait tile kt+1 only; tile kt+2 stays in flight across the barrier
        if (kt + 2 < NK) asm volatile("s_waitcnt vmcnt(6)" ::: "memory");
        else             asm volatile("s_waitcnt vmcnt(0)" ::: "memory");
        __builtin_amdgcn_s_barrier();          // all waves: buf[cur^1] ready
    }

    #pragma unroll
    for (int n = 0; n < 8; ++n) {
        int col = n0 + wc * 128 + n * 16 + ar;
        float bv = bias[col];
        #pragma unroll
        for (int m = 0; m < 4; ++m) {
            #pragma unroll
            for (int r = 0; r < 4; ++r) {
                int row = m0 + wr * 64 + m * 16 + ((lane >> 4) << 2) + r;
                C[(size_t)row * N + col] = acc[m][n][r] + bv;
            }
        }
    }
}

// ---------------- ctx GEMM (kv projections, reg-staged fp32->fp16) ----------
#define PK 40

template<int OUTM>
__global__ __launch_bounds__(256) void gemm_ctx(
    const float* __restrict__ A, const f16* __restrict__ Bt,
    f16* __restrict__ CH, int M, int N, int K)
{
    __shared__ f16 lA[128 * PK];
    __shared__ f16 lB[128 * PK];

    const int t = threadIdx.x;
    const int lane = t & 63;
    const int wid = t >> 6;
    const int wr = wid >> 1, wc = wid & 1;
    const int m0 = blockIdx.x * 128, n0 = blockIdx.y * 128;
    const int ar = lane & 15;
    const int kc = (lane >> 4) << 3;

    f32x4 acc[4][4] = {};

    for (int k0 = 0; k0 < K; k0 += 32) {
        #pragma unroll
        for (int it = 0; it < 4; ++it) {
            int idx = t + it * 256;
            int row = idx >> 3;
            int c4 = (idx & 7) << 2;
            int gr = m0 + row;
            float4 v = make_float4(0.f, 0.f, 0.f, 0.f);
            if (gr < M) v = *(const float4*)(A + (size_t)gr * K + k0 + c4);
            *(half4*)(lA + row * PK + c4) = (half4){(f16)v.x, (f16)v.y, (f16)v.z, (f16)v.w};
        }
        #pragma unroll
        for (int it = 0; it < 2; ++it) {
            int idx = t + it * 256;
            int row = idx >> 2;
            int c8 = (idx & 3) << 3;
            *(half8*)(lB + row * PK + c8) =
                *(const half8*)(Bt + (size_t)(n0 + row) * K + k0 + c8);
        }
        __syncthreads();

        half8 fa[4], fb[4];
        #pragma unroll
        for (int m = 0; m < 4; ++m)
            fa[m] = *(const half8*)(lA + (wr * 64 + m * 16 + ar) * PK + kc);
        #pragma unroll
        for (int n = 0; n < 4; ++n)
            fb[n] = *(const half8*)(lB + (wc * 64 + n * 16 + ar) * PK + kc);
        #pragma unroll
        for (int m = 0; m < 4; ++m)
            #pragma unroll
            for (int n = 0; n < 4; ++n)
                acc[m][n] = mfma16h(fa[m], fb[n], acc[m][n]);
        __syncthreads();
    }

    #pragma unroll
    for (int n = 0; n < 4; ++n) {
        int col = n0 + wc * 64 + n * 16 + ar;
        #pragma unroll
        for (int m = 0; m < 4; ++m) {
            #pragma unroll
            for (int r = 0; r < 4; ++r) {
                int row = m0 + wr * 64 + m * 16 + ((lane >> 4) << 2) + r;
                if (row < M) {
                    float v = acc[m][n][r];
                    if constexpr (OUTM == OUT_H) {
                        CH[(size_t)row * N + col] = (f16)v;
                    } else {
                        int bb = row / 77;
                        int si = row - bb * 77;
                        CH[((size_t)bb * 512 + col) * 96 + si] = (f16)v;
                    }
                }
            }
        }
    }
}

// ---------------- MFMA attention (fp16 inputs, fp32 softmax) ----------------
// grid (Sq/128, H, B), block 256 (4 waves, 32 q-rows each).
__global__ __launch_bounds__(256) void attn_h16(
    const f16* __restrict__ q, const f16* __restrict__ k,
    const f16* __restrict__ vT, f16* __restrict__ outA)
{
    constexpr int PST = 104;   // P LDS stride (f16): rows 16B-aligned
    __shared__ f16 sP[4 * 32 * PST];

    const int t = threadIdx.x;
    const int lane = t & 63;
    const int w = t >> 6;
    const int ar = lane & 15;
    const int kg = lane >> 4;
    const int kc = kg << 3;
    const int b = blockIdx.z, head = blockIdx.y;
    const size_t qrow0 = (size_t)b * 4096 + blockIdx.x * 128 + w * 32;

    // ---- scores [32 q][80 si], K-dim = 64 ----
    f32x4 accs[2][5] = {};
    #pragma unroll
    for (int ks = 0; ks < 2; ++ks) {
        const int d = head * 64 + ks * 32 + kc;
        half8 ah[2];
        #pragma unroll
        for (int m = 0; m < 2; ++m)
            ah[m] = *(const half8*)(q + (qrow0 + m * 16 + ar) * 512 + d);
        #pragma unroll
        for (int n = 0; n < 5; ++n) {
            half8 bh = *(const half8*)(k + ((size_t)(b * 77 + n * 16 + ar)) * 512 + d);
            #pragma unroll
            for (int m = 0; m < 2; ++m)
                accs[m][n] = mfma16h(ah[m], bh, accs[m][n]);
        }
    }

    // ---- softmax in registers (rows on 16-lane groups) ----
    #pragma unroll
    for (int m = 0; m < 2; ++m) {
        #pragma unroll
        for (int r = 0; r < 4; ++r) {
            float mx = -1e30f;
            #pragma unroll
            for (int n = 0; n < 5; ++n) {
                float v = accs[m][n][r] * 0.125f;          // * D_HEAD^-0.5
                if (n == 4 && ar >= 13) v = -1e30f;        // mask si >= 77
                accs[m][n][r] = v;
                mx = fmaxf(mx, v);
            }
            mx = fmaxf(mx, __shfl_xor(mx, 1));
            mx = fmaxf(mx, __shfl_xor(mx, 2));
            mx = fmaxf(mx, __shfl_xor(mx, 4));
            mx = fmaxf(mx, __shfl_xor(mx, 8));
            float sum = 0.f;
            #pragma unroll
            for (int n = 0; n < 5; ++n) {
                float e = __expf(accs[m][n][r] - mx);
                accs[m][n][r] = e;
                sum += e;
            }
            sum += __shfl_xor(sum, 1);
            sum += __shfl_xor(sum, 2);
            sum += __shfl_xor(sum, 4);
            sum += __shfl_xor(sum, 8);
            float inv = 1.f / sum;
            #pragma unroll
            for (int n = 0; n < 5; ++n) accs[m][n][r] *= inv;
        }
    }

    // ---- P -> LDS fp16, zero-pad cols 80..103 ----
    f16* myP = sP + w * 32 * PST;
    for (int i = lane; i < 32 * 12; i += 64) {
        int row = i / 12, c = 80 + (i % 12) * 2;
        *(u32*)(myP + row * PST + c) = 0;
    }
    #pragma unroll
    for (int m = 0; m < 2; ++m)
        #pragma unroll
        for (int n = 0; n < 5; ++n)
            #pragma unroll
            for (int r = 0; r < 4; ++r)
                myP[(m * 16 + kg * 4 + r) * PST + n * 16 + ar] = (f16)accs[m][n][r];
    __syncthreads();

    // ---- PV [32 q][64 d], K-dim = 96 (zero-padded) ----
    f32x4 accp[2][4] = {};
    #pragma unroll
    for (int ks = 0; ks < 3; ++ks) {
        half8 pa[2];
        #pragma unroll
        for (int m = 0; m < 2; ++m)
            pa[m] = *(const half8*)(myP + (m * 16 + ar) * PST + ks * 32 + kc);
        #pragma unroll
        for (int n = 0; n < 4; ++n) {
            half8 bh = *(const half8*)(vT + ((size_t)b * 512 + head * 64 + n * 16 + ar) * 96 + ks * 32 + kc);
            #pragma unroll
            for (int m = 0; m < 2; ++m)
                accp[m][n] = mfma16h(pa[m], bh, accp[m][n]);
        }
    }

    // ---- store attn output fp16 ----
    #pragma unroll
    for (int m = 0; m < 2; ++m)
        #pragma unroll
        for (int n = 0; n < 4; ++n)
            #pragma unroll
            for (int r = 0; r < 4; ++r)
                outA[(qrow0 + m * 16 + kg * 4 + r) * 512 + head * 64 + n * 16 + ar]
                    = (f16)accp[m][n][r];
}

extern "C" void kernel_launch(void* const* d_in, const int* in_sizes, int n_in,
                              void* d_out, int out_size, void* d_ws, size_t ws_size,
                              hipStream_t stream)
{
    const float* x    = (const float*)d_in[0];   // [16,4096,512]
    const float* ctx  = (const float*)d_in[1];   // [16,77,768]
    const float* Wq   = (const float*)d_in[2];   // [512,512]
    const float* Wk   = (const float*)d_in[3];   // [768,512]
    const float* Wv   = (const float*)d_in[4];   // [768,512]
    const float* Wout = (const float*)d_in[5];   // [512,512]
    const float* bout = (const float*)d_in[6];   // [512]

    char* ws = (char*)d_ws;
    size_t off = 0;
    auto alloc = [&](size_t bytes) -> void* {
        void* p = ws + off;
        off += (bytes + 255) & ~(size_t)255;
        return p;
    };
    f16* WqT = (f16*)alloc(512 * 512 * 2);
    f16* WkT = (f16*)alloc(768 * 512 * 2);
    f16* WvT = (f16*)alloc(768 * 512 * 2);
    f16* WoT = (f16*)alloc(512 * 512 * 2);
    f16* kbuf = (f16*)alloc((size_t)1240 * 512 * 2);     // 1232 rows + zero pad
    f16* vT   = (f16*)alloc((size_t)16 * 512 * 96 * 2);  // [b][col][si pad 96]
    f16* qh   = (f16*)alloc((size_t)65536 * 512 * 2);    // q fp16 (64 MiB)
    f16* attnA = (f16*)alloc((size_t)65536 * 512 * 2);   // attn output (64 MiB)
    (void)ws_size; (void)in_sizes; (void)n_in; (void)out_size;

    // 0. zero pads
    pad_fill<<<dim3(625), dim3(256), 0, stream>>>(vT, kbuf);

    // 1. weight transposes -> fp16 (one launch)
    transpose4<<<dim3(5120), dim3(256), 0, stream>>>(
        Wq, Wk, Wv, Wout, WqT, WkT, WvT, WoT);

    // 2. k/v projections
    gemm_ctx<OUT_H><<<dim3(10, 4), dim3(256), 0, stream>>>(
        ctx, WkT, kbuf, 1232, 512, 768);
    gemm_ctx<OUT_HT><<<dim3(10, 4), dim3(256), 0, stream>>>(
        ctx, WvT, vT, 1232, 512, 768);

    // 3. q projection (cvt fused): x fp32 @ WqT -> q fp16 in ws
    gemm_x16<<<dim3(2, 512), dim3(256), 0, stream>>>(
        x, WqT, qh, 65536, 512, 512);

    // 4. attention -> attn fp16
    attn_h16<<<dim3(32, 8, 16), dim3(256), 0, stream>>>(qh, kbuf, vT, attnA);

    // 5. output projection + bias -> d_out fp32 (counted-vmcnt pipeline)
    gemm_h16<<<dim3(2, 512), dim3(256), 0, stream>>>(
        attnA, WoT, bout, (float*)d_out, 65536, 512, 512);
}

// Round 15
// 223.350 us; speedup vs baseline: 1.3399x; 1.3346x over previous
//
#include <hip/hip_runtime.h>

// CrossAttention: B=16, Sq=4096, Dm=512, Skv=77, Dc=768, H=8, Dh=64, inner=512
// Single-pass fp16 MFMA pipeline (R12 GEMM structure).
//   0. pad_fill : zero vT si-pad + kbuf row-pad
//   1. transpose4: all W* fp32 [K][512] -> fp16 [512][K] in one launch  (ws)
//   2. gemm_kv  : MERGED k+v projections, ctx @ [Wk|Wv], 64x64 tiles,
//                 320 blocks (was 2 kernels x 40 blocks = GPU 85% idle)  (ws)
//   3. gemm_x16 : q = x(fp32)@Wq -> fp16 [65536][512]  (cvt fused)      (ws)
//   4. attn_h16 : MFMA scores + in-reg fp32 softmax + MFMA PV           (ws)
//                 (no block barrier: P is wave-private)
//   5. gemm_h16 : out = attn@Wout + bout -> fp32                        (d_out)
// Big GEMMs: 128x256 tile, dbuf LDS, issue-early loads, __syncthreads sync.

typedef unsigned short u16;
typedef unsigned int u32;
typedef _Float16 f16;
typedef __attribute__((ext_vector_type(8))) _Float16 half8;
typedef __attribute__((ext_vector_type(4))) _Float16 half4;
typedef __attribute__((ext_vector_type(4))) float f32x4;

__device__ __forceinline__ f32x4 mfma16h(half8 a, half8 b, f32x4 c) {
    return __builtin_amdgcn_mfma_f32_16x16x32_f16(a, b, c, 0, 0, 0);
}
// async global->LDS, 16B per lane; LDS dest = wave-uniform base + lane*16
__device__ __forceinline__ void gl_lds16(const f16* g, f16* l) {
    __builtin_amdgcn_global_load_lds(
        (const __attribute__((address_space(1))) void*)g,
        (__attribute__((address_space(3))) void*)l, 16, 0, 0);
}

// ---------------- pad fill ----------------
__global__ __launch_bounds__(256) void pad_fill(
    f16* __restrict__ vT, f16* __restrict__ kbuf)
{
    const int nv = 16 * 512 * 19;
    int i = blockIdx.x * 256 + threadIdx.x;
    if (i < nv) {
        int g = i / 19, s = i - g * 19;
        vT[(size_t)g * 96 + 77 + s] = (f16)0.f;
    } else {
        int j = i - nv;
        if (j < 8 * 512) kbuf[(size_t)1232 * 512 + j] = (f16)0.f;
    }
}

// ---------------- all 4 weight transposes -> fp16, one launch ----------------
__global__ __launch_bounds__(256) void transpose4(
    const float* __restrict__ Wq, const float* __restrict__ Wk,
    const float* __restrict__ Wv, const float* __restrict__ Wo,
    f16* __restrict__ WqT, f16* __restrict__ WkT,
    f16* __restrict__ WvT, f16* __restrict__ WoT)
{
    int idx = blockIdx.x * 256 + threadIdx.x;
    const float* W; f16* T; int K; int base;
    if (idx < 262144)        { W = Wq; T = WqT; K = 512; base = 0; }
    else if (idx < 655360)   { W = Wk; T = WkT; K = 768; base = 262144; }
    else if (idx < 1048576)  { W = Wv; T = WvT; K = 768; base = 655360; }
    else if (idx < 1310720)  { W = Wo; T = WoT; K = 512; base = 1048576; }
    else return;
    int j = idx - base;
    int n = j / K, k = j - n * K;
    T[j] = (f16)W[(size_t)k * 512 + n];
}

// ---------------- MERGED k/v projection: ctx @ [Wk|Wv] ----------------
// A fp32 [1232][768]; Bt fp16 [1024][768] (WkT rows 0-511, WvT rows 512-1023,
// allocated adjacently). 64x64 tiles, grid (20,16), block 256 (2x2 waves 32x32).
// N-half 0: kbuf[row][col]; N-half 1: vT[(b*512+col-512)*96 + si].
__global__ __launch_bounds__(256) void gemm_kv(
    const float* __restrict__ A, const f16* __restrict__ Bt,
    f16* __restrict__ kbuf, f16* __restrict__ vT)
{
    __shared__ f16 lA[64 * 40];
    __shared__ f16 lB[64 * 40];

    const int t = threadIdx.x;
    const int lane = t & 63;
    const int w = t >> 6;
    const int wr = w >> 1, wc = w & 1;
    const int m0 = blockIdx.x * 64, n0 = blockIdx.y * 64;
    const int ar = lane & 15;
    const int kc = (lane >> 4) << 3;

    const int srow = t >> 2;          // 0..63
    const int sc8  = (t & 3) << 3;    // 0,8,16,24

    f32x4 acc[2][2] = {};

    for (int k0 = 0; k0 < 768; k0 += 32) {
        float4 v0 = make_float4(0.f, 0.f, 0.f, 0.f);
        float4 v1 = make_float4(0.f, 0.f, 0.f, 0.f);
        int gr = m0 + srow;
        if (gr < 1232) {
            v0 = *(const float4*)(A + (size_t)gr * 768 + k0 + sc8);
            v1 = *(const float4*)(A + (size_t)gr * 768 + k0 + sc8 + 4);
        }
        half8 ha = {(f16)v0.x, (f16)v0.y, (f16)v0.z, (f16)v0.w,
                    (f16)v1.x, (f16)v1.y, (f16)v1.z, (f16)v1.w};
        *(half8*)(lA + srow * 40 + sc8) = ha;
        *(half8*)(lB + srow * 40 + sc8) =
            *(const half8*)(Bt + (size_t)(n0 + srow) * 768 + k0 + sc8);
        __syncthreads();

        half8 fa[2], fb[2];
        #pragma unroll
        for (int m = 0; m < 2; ++m)
            fa[m] = *(const half8*)(lA + (wr * 32 + m * 16 + ar) * 40 + kc);
        #pragma unroll
        for (int n = 0; n < 2; ++n)
            fb[n] = *(const half8*)(lB + (wc * 32 + n * 16 + ar) * 40 + kc);
        #pragma unroll
        for (int m = 0; m < 2; ++m)
            #pragma unroll
            for (int n = 0; n < 2; ++n)
                acc[m][n] = mfma16h(fa[m], fb[n], acc[m][n]);
        __syncthreads();
    }

    #pragma unroll
    for (int n = 0; n < 2; ++n) {
        int col = n0 + wc * 32 + n * 16 + ar;
        #pragma unroll
        for (int m = 0; m < 2; ++m) {
            #pragma unroll
            for (int r = 0; r < 4; ++r) {
                int row = m0 + wr * 32 + m * 16 + ((lane >> 4) << 2) + r;
                if (row < 1232) {
                    f16 v = (f16)acc[m][n][r];
                    if (col < 512) {
                        kbuf[(size_t)row * 512 + col] = v;
                    } else {
                        int bb = row / 77;
                        int si = row - bb * 77;
                        vT[((size_t)bb * 512 + (col - 512)) * 96 + si] = v;
                    }
                }
            }
        }
    }
}

// ---------------- q-proj GEMM: fused fp32->fp16, 128x256 tile (R12) --------
__global__ __launch_bounds__(256, 2) void gemm_x16(
    const float* __restrict__ A, const f16* __restrict__ B,
    f16* __restrict__ CHalf, int M, int N, int K)
{
    __shared__ f16 sA[2][128 * 32];
    __shared__ f16 sB[2][256 * 32];

    const int t = threadIdx.x;
    const int lane = t & 63;
    const int w = t >> 6;
    const int wr = w >> 1, wc = w & 1;

    const int f = blockIdx.x + gridDim.x * blockIdx.y;
    const int cpx = (gridDim.x * gridDim.y) >> 3;
    const int logical = (f & 7) * cpx + (f >> 3);
    const int m0 = (logical / gridDim.x) * 128;
    const int n0 = (logical % gridDim.x) * 256;

    const int ar = lane & 15;
    const int kc = (lane >> 4) << 3;

    const int arow = t >> 1;
    const int acol = (t & 1) << 4;
    const int brow = lane >> 2;
    const int bcol = (lane & 3) << 3;

    f32x4 acc[4][8] = {};
    f32x4 rA[4];

    auto LOAD_A = [&](int kt) {
        const float* p = A + (size_t)(m0 + arow) * K + (kt << 5) + acol;
        #pragma unroll
        for (int j = 0; j < 4; ++j) rA[j] = *(const f32x4*)(p + j * 4);
    };
    auto WRITE_A = [&](int buf) {
        half8 h0 = { (f16)rA[0].x, (f16)rA[0].y, (f16)rA[0].z, (f16)rA[0].w,
                     (f16)rA[1].x, (f16)rA[1].y, (f16)rA[1].z, (f16)rA[1].w };
        half8 h1 = { (f16)rA[2].x, (f16)rA[2].y, (f16)rA[2].z, (f16)rA[2].w,
                     (f16)rA[3].x, (f16)rA[3].y, (f16)rA[3].z, (f16)rA[3].w };
        *(half8*)(&sA[buf][arow * 32 + acol])     = h0;
        *(half8*)(&sA[buf][arow * 32 + acol + 8]) = h1;
    };
    auto STAGE_B = [&](int buf, int kt) {
        #pragma unroll
        for (int j = 0; j < 4; ++j) {
            const int ci = w * 4 + j;
            gl_lds16(B + (size_t)(n0 + ci * 16 + brow) * K + (kt << 5) + bcol,
                     &sB[buf][ci * 512]);
        }
    };

    const int nk = K >> 5;
    LOAD_A(0);
    STAGE_B(0, 0);
    WRITE_A(0);
    __syncthreads();

    int cur = 0;
    for (int kt = 0; kt < nk; ++kt) {
        if (kt + 1 < nk) {
            LOAD_A(kt + 1);
            STAGE_B(cur ^ 1, kt + 1);
        }

        half8 fa[4], fb[8];
        #pragma unroll
        for (int m = 0; m < 4; ++m)
            fa[m] = *(const half8*)(&sA[cur][(wr * 64 + m * 16 + ar) * 32 + kc]);
        #pragma unroll
        for (int n = 0; n < 8; ++n)
            fb[n] = *(const half8*)(&sB[cur][(wc * 128 + n * 16 + ar) * 32 + kc]);

        __builtin_amdgcn_s_setprio(1);
        #pragma unroll
        for (int m = 0; m < 4; ++m)
            #pragma unroll
            for (int n = 0; n < 8; ++n)
                acc[m][n] = mfma16h(fa[m], fb[n], acc[m][n]);
        __builtin_amdgcn_s_setprio(0);

        if (kt + 1 < nk) WRITE_A(cur ^ 1);
        __syncthreads();
        cur ^= 1;
    }

    #pragma unroll
    for (int n = 0; n < 8; ++n) {
        int col = n0 + wc * 128 + n * 16 + ar;
        #pragma unroll
        for (int m = 0; m < 4; ++m) {
            #pragma unroll
            for (int r = 0; r < 4; ++r) {
                int row = m0 + wr * 64 + m * 16 + ((lane >> 4) << 2) + r;
                CHalf[(size_t)row * N + col] = (f16)acc[m][n][r];
            }
        }
    }
}

// ---------------- out-proj GEMM: fp16, 128x256 tile, gl_lds dbuf (R12) -----
__global__ __launch_bounds__(256, 2) void gemm_h16(
    const f16* __restrict__ A, const f16* __restrict__ B,
    const float* __restrict__ bias, float* __restrict__ C,
    int M, int N, int K)
{
    __shared__ f16 sA[2][128 * 32];
    __shared__ f16 sB[2][256 * 32];

    const int t = threadIdx.x;
    const int lane = t & 63;
    const int w = t >> 6;
    const int wr = w >> 1, wc = w & 1;

    const int f = blockIdx.x + gridDim.x * blockIdx.y;
    const int cpx = (gridDim.x * gridDim.y) >> 3;
    const int logical = (f & 7) * cpx + (f >> 3);
    const int m0 = (logical / gridDim.x) * 128;
    const int n0 = (logical % gridDim.x) * 256;

    const int ar = lane & 15;
    const int kc = (lane >> 4) << 3;
    const int srow = lane >> 2;
    const int scol = (lane & 3) << 3;

    f32x4 acc[4][8] = {};

    auto STAGE = [&](int buf, int kt) {
        #pragma unroll
        for (int j = 0; j < 2; ++j) {
            const int ci = w * 2 + j;
            gl_lds16(A + (size_t)(m0 + ci * 16 + srow) * K + (kt << 5) + scol,
                     &sA[buf][ci * 512]);
        }
        #pragma unroll
        for (int j = 0; j < 4; ++j) {
            const int ci = w * 4 + j;
            gl_lds16(B + (size_t)(n0 + ci * 16 + srow) * K + (kt << 5) + scol,
                     &sB[buf][ci * 512]);
        }
    };

    const int nk = K >> 5;
    STAGE(0, 0);
    __syncthreads();

    int cur = 0;
    for (int kt = 0; kt < nk; ++kt) {
        if (kt + 1 < nk) STAGE(cur ^ 1, kt + 1);

        half8 fa[4], fb[8];
        #pragma unroll
        for (int m = 0; m < 4; ++m)
            fa[m] = *(const half8*)(&sA[cur][(wr * 64 + m * 16 + ar) * 32 + kc]);
        #pragma unroll
        for (int n = 0; n < 8; ++n)
            fb[n] = *(const half8*)(&sB[cur][(wc * 128 + n * 16 + ar) * 32 + kc]);

        __builtin_amdgcn_s_setprio(1);
        #pragma unroll
        for (int m = 0; m < 4; ++m)
            #pragma unroll
            for (int n = 0; n < 8; ++n)
                acc[m][n] = mfma16h(fa[m], fb[n], acc[m][n]);
        __builtin_amdgcn_s_setprio(0);
        __syncthreads();
        cur ^= 1;
    }

    #pragma unroll
    for (int n = 0; n < 8; ++n) {
        int col = n0 + wc * 128 + n * 16 + ar;
        float bv = bias[col];
        #pragma unroll
        for (int m = 0; m < 4; ++m) {
            #pragma unroll
            for (int r = 0; r < 4; ++r) {
                int row = m0 + wr * 64 + m * 16 + ((lane >> 4) << 2) + r;
                C[(size_t)row * N + col] = acc[m][n][r] + bv;
            }
        }
    }
}

// ---------------- MFMA attention (fp16 inputs, fp32 softmax) ----------------
// grid (Sq/128, H, B), block 256 (4 waves, 32 q-rows each).
// P is wave-private LDS -> no block barrier anywhere.
__global__ __launch_bounds__(256) void attn_h16(
    const f16* __restrict__ q, const f16* __restrict__ k,
    const f16* __restrict__ vT, f16* __restrict__ outA)
{
    constexpr int PST = 104;
    __shared__ f16 sP[4 * 32 * PST];

    const int t = threadIdx.x;
    const int lane = t & 63;
    const int w = t >> 6;
    const int ar = lane & 15;
    const int kg = lane >> 4;
    const int kc = kg << 3;
    const int b = blockIdx.z, head = blockIdx.y;
    const size_t qrow0 = (size_t)b * 4096 + blockIdx.x * 128 + w * 32;

    // ---- scores [32 q][80 si], K-dim = 64 ----
    f32x4 accs[2][5] = {};
    #pragma unroll
    for (int ks = 0; ks < 2; ++ks) {
        const int d = head * 64 + ks * 32 + kc;
        half8 ah[2];
        #pragma unroll
        for (int m = 0; m < 2; ++m)
            ah[m] = *(const half8*)(q + (qrow0 + m * 16 + ar) * 512 + d);
        #pragma unroll
        for (int n = 0; n < 5; ++n) {
            half8 bh = *(const half8*)(k + ((size_t)(b * 77 + n * 16 + ar)) * 512 + d);
            #pragma unroll
            for (int m = 0; m < 2; ++m)
                accs[m][n] = mfma16h(ah[m], bh, accs[m][n]);
        }
    }

    // ---- softmax in registers (rows on 16-lane groups) ----
    #pragma unroll
    for (int m = 0; m < 2; ++m) {
        #pragma unroll
        for (int r = 0; r < 4; ++r) {
            float mx = -1e30f;
            #pragma unroll
            for (int n = 0; n < 5; ++n) {
                float v = accs[m][n][r] * 0.125f;
                if (n == 4 && ar >= 13) v = -1e30f;   // mask si >= 77
                accs[m][n][r] = v;
                mx = fmaxf(mx, v);
            }
            mx = fmaxf(mx, __shfl_xor(mx, 1));
            mx = fmaxf(mx, __shfl_xor(mx, 2));
            mx = fmaxf(mx, __shfl_xor(mx, 4));
            mx = fmaxf(mx, __shfl_xor(mx, 8));
            float sum = 0.f;
            #pragma unroll
            for (int n = 0; n < 5; ++n) {
                float e = __expf(accs[m][n][r] - mx);
                accs[m][n][r] = e;
                sum += e;
            }
            sum += __shfl_xor(sum, 1);
            sum += __shfl_xor(sum, 2);
            sum += __shfl_xor(sum, 4);
            sum += __shfl_xor(sum, 8);
            float inv = 1.f / sum;
            #pragma unroll
            for (int n = 0; n < 5; ++n) accs[m][n][r] *= inv;
        }
    }

    // ---- P -> wave-private LDS fp16, zero-pad cols 80..103 ----
    f16* myP = sP + w * 32 * PST;
    for (int i = lane; i < 32 * 12; i += 64) {
        int row = i / 12, c = 80 + (i % 12) * 2;
        *(u32*)(myP + row * PST + c) = 0;
    }
    #pragma unroll
    for (int m = 0; m < 2; ++m)
        #pragma unroll
        for (int n = 0; n < 5; ++n)
            #pragma unroll
            for (int r = 0; r < 4; ++r)
                myP[(m * 16 + kg * 4 + r) * PST + n * 16 + ar] = (f16)accs[m][n][r];
    // no barrier: within-wave ds ordering via lgkmcnt

    // ---- PV [32 q][64 d], K-dim = 96 (zero-padded) ----
    f32x4 accp[2][4] = {};
    #pragma unroll
    for (int ks = 0; ks < 3; ++ks) {
        half8 pa[2];
        #pragma unroll
        for (int m = 0; m < 2; ++m)
            pa[m] = *(const half8*)(myP + (m * 16 + ar) * PST + ks * 32 + kc);
        #pragma unroll
        for (int n = 0; n < 4; ++n) {
            half8 bh = *(const half8*)(vT + ((size_t)b * 512 + head * 64 + n * 16 + ar) * 96 + ks * 32 + kc);
            #pragma unroll
            for (int m = 0; m < 2; ++m)
                accp[m][n] = mfma16h(pa[m], bh, accp[m][n]);
        }
    }

    // ---- store attn output fp16 ----
    #pragma unroll
    for (int m = 0; m < 2; ++m)
        #pragma unroll
        for (int n = 0; n < 4; ++n)
            #pragma unroll
            for (int r = 0; r < 4; ++r)
                outA[(qrow0 + m * 16 + kg * 4 + r) * 512 + head * 64 + n * 16 + ar]
                    = (f16)accp[m][n][r];
}

extern "C" void kernel_launch(void* const* d_in, const int* in_sizes, int n_in,
                              void* d_out, int out_size, void* d_ws, size_t ws_size,
                              hipStream_t stream)
{
    const float* x    = (const float*)d_in[0];   // [16,4096,512]
    const float* ctx  = (const float*)d_in[1];   // [16,77,768]
    const float* Wq   = (const float*)d_in[2];   // [512,512]
    const float* Wk   = (const float*)d_in[3];   // [768,512]
    const float* Wv   = (const float*)d_in[4];   // [768,512]
    const float* Wout = (const float*)d_in[5];   // [512,512]
    const float* bout = (const float*)d_in[6];   // [512]

    char* ws = (char*)d_ws;
    size_t off = 0;
    auto alloc = [&](size_t bytes) -> void* {
        void* p = ws + off;
        off += (bytes + 255) & ~(size_t)255;
        return p;
    };
    f16* WqT = (f16*)alloc(512 * 512 * 2);
    f16* WkT = (f16*)alloc(768 * 512 * 2);     // 786432 B (256-aligned) ...
    f16* WvT = (f16*)alloc(768 * 512 * 2);     // ... so WvT == WkT + 768*512 (adjacent)
    f16* WoT = (f16*)alloc(512 * 512 * 2);
    f16* kbuf = (f16*)alloc((size_t)1240 * 512 * 2);     // 1232 rows + zero pad
    f16* vT   = (f16*)alloc((size_t)16 * 512 * 96 * 2);  // [b][col][si pad 96]
    f16* qh   = (f16*)alloc((size_t)65536 * 512 * 2);    // q fp16 (64 MiB)
    f16* attnA = (f16*)alloc((size_t)65536 * 512 * 2);   // attn output (64 MiB)
    (void)ws_size; (void)in_sizes; (void)n_in; (void)out_size;

    // 0. zero pads
    pad_fill<<<dim3(625), dim3(256), 0, stream>>>(vT, kbuf);

    // 1. weight transposes -> fp16 (one launch)
    transpose4<<<dim3(5120), dim3(256), 0, stream>>>(
        Wq, Wk, Wv, Wout, WqT, WkT, WvT, WoT);

    // 2. merged k/v projection: 320 blocks (was 2 x 40)
    gemm_kv<<<dim3(20, 16), dim3(256), 0, stream>>>(ctx, WkT, kbuf, vT);

    // 3. q projection (cvt fused): x fp32 @ WqT -> q fp16 in ws
    gemm_x16<<<dim3(2, 512), dim3(256), 0, stream>>>(
        x, WqT, qh, 65536, 512, 512);

    // 4. attention -> attn fp16
    attn_h16<<<dim3(32, 8, 16), dim3(256), 0, stream>>>(qh, kbuf, vT, attnA);

    // 5. output projection + bias -> d_out fp32
    gemm_h16<<<dim3(2, 512), dim3(256), 0, stream>>>(
        attnA, WoT, bout, (float*)d_out, 65536, 512, 512);
}